// Round 21
// baseline (123.430 us; speedup 1.0000x reference)
//
#include <hip/hip_runtime.h>
#include <hip/hip_bf16.h>

#define B_ 8
#define S_ 2048
#define D_ 512

typedef __attribute__((ext_vector_type(8))) short short8;
typedef __attribute__((ext_vector_type(4))) float f32x4;

static __device__ __forceinline__ unsigned short f2bf(float f) {
    union { float f; unsigned u; } v; v.f = f;
    unsigned r = v.u + 0x7FFFu + ((v.u >> 16) & 1u);   // round-nearest-even
    return (unsigned short)(r >> 16);
}

static __device__ __forceinline__ float fexp2(float x) {   // 2^x, native
    float r; asm("v_exp_f32 %0, %1" : "=v"(r) : "v"(x)); return r;
}

static __device__ __forceinline__ void gl_lds16(const void* g, void* l) {
    __builtin_amdgcn_global_load_lds(
        (const __attribute__((address_space(1))) unsigned int*)g,
        (__attribute__((address_space(3))) unsigned int*)l, 16, 0, 0);
}

// ---------------- stage 0 (fused): x->bf16, W->bf16^T, l=0 ------------------
__global__ void k_prep(const float* __restrict__ x,
                       const float* __restrict__ Wq, const float* __restrict__ Wk,
                       const float* __restrict__ Wv,
                       unsigned short* __restrict__ xb, unsigned short* __restrict__ Wt,
                       float* __restrict__ l) {
    int bid = blockIdx.x;
    if (bid < 4096) {
        int i = bid * 256 + threadIdx.x;             // one thread per 8 elems
        const float4* p = (const float4*)x + (size_t)i * 2;
        float4 a = p[0], b = p[1];
        union { unsigned short u[8]; uint4 v; } o;
        o.u[0] = f2bf(a.x); o.u[1] = f2bf(a.y); o.u[2] = f2bf(a.z); o.u[3] = f2bf(a.w);
        o.u[4] = f2bf(b.x); o.u[5] = f2bf(b.y); o.u[6] = f2bf(b.z); o.u[7] = f2bf(b.w);
        ((uint4*)xb)[i] = o.v;
    } else if (bid < 7168) {
        int idx = (bid - 4096) * 256 + threadIdx.x;  // 0 .. 3*512*512-1
        int z = idx >> 18;
        int r = idx & 262143;
        int e = r >> 9, d = r & 511;
        const float* W = (z == 0) ? Wq : ((z == 1) ? Wk : Wv);
        Wt[idx] = f2bf(W[d * 512 + e]);
    } else {
        l[(bid - 7168) * 256 + threadIdx.x] = 0.f;
    }
}

// ---------------- stage 1: QKV projection GEMM (LDS-staged, 128x128) --------
__global__ __launch_bounds__(256, 4) void k_qkv(
    const unsigned short* __restrict__ xb, const unsigned short* __restrict__ Wt,
    const float* __restrict__ biasq, const float* __restrict__ biask,
    const float* __restrict__ biasv,
    unsigned short* __restrict__ Qb, unsigned short* __restrict__ Kb,
    unsigned short* __restrict__ Vs) {
  __shared__ __align__(16) unsigned char smA[16384];   // A tile [128 m][64 k], swz
  __shared__ __align__(16) unsigned char smB[16384];   // B tile [128 n][64 k], swz
  const int z = blockIdx.z;
  const unsigned short* W = Wt + (size_t)z * (D_ * D_);
  const int lane = threadIdx.x & 63, wid = threadIdx.x >> 6;
  const int c = lane & 15, g = lane >> 4;
  const int wr = wid >> 1, wc = wid & 1;
  const int m_blk = blockIdx.x * 128;
  const int n_blk = blockIdx.y * 128;

  const int src_sw = ((lane & 7) * 16) ^ (((lane >> 3) & 7) << 4);
  const unsigned char* ga = (const unsigned char*)xb
      + (size_t)(m_blk + wid * 32 + (lane >> 3)) * 1024;
  const unsigned char* gb = (const unsigned char*)W
      + (size_t)(n_blk + wid * 32 + (lane >> 3)) * 1024;
  unsigned char* la = smA + wid * 4096;
  unsigned char* lb = smB + wid * 4096;

  f32x4 acc[4][4];
#pragma unroll
  for (int mi = 0; mi < 4; ++mi)
#pragma unroll
    for (int ni = 0; ni < 4; ++ni) acc[mi][ni] = (f32x4){0.f, 0.f, 0.f, 0.f};

  for (int step = 0; step < 8; ++step) {
    __syncthreads();                                  // prev-tile reads done
#pragma unroll
    for (int i = 0; i < 4; ++i) {
      gl_lds16(ga + (size_t)i * 8192 + step * 128 + src_sw, la + i * 1024);
      gl_lds16(gb + (size_t)i * 8192 + step * 128 + src_sw, lb + i * 1024);
    }
    __syncthreads();                                  // staged data visible
#pragma unroll
    for (int kc = 0; kc < 2; ++kc) {
      const int ro = (kc * 64 + g * 16) ^ ((c & 7) << 4);
      short8 af[4], bf[4];
#pragma unroll
      for (int mi = 0; mi < 4; ++mi)
        af[mi] = *(const short8*)(smA + (wr * 64 + mi * 16 + c) * 128 + ro);
#pragma unroll
      for (int ni = 0; ni < 4; ++ni)
        bf[ni] = *(const short8*)(smB + (wc * 64 + ni * 16 + c) * 128 + ro);
#pragma unroll
      for (int mi = 0; mi < 4; ++mi)
#pragma unroll
        for (int ni = 0; ni < 4; ++ni)
          acc[mi][ni] = __builtin_amdgcn_mfma_f32_16x16x32_bf16(af[mi], bf[ni], acc[mi][ni], 0, 0, 0);
    }
  }

  const int m0 = m_blk + wr * 64;
  const int n0 = n_blk + wc * 64;
  if (z < 2) {
    const float* bias = (z == 0) ? biasq : biask;
    unsigned short* outp = (z == 0) ? Qb : Kb;
    // z=0: log2(e)/sqrt(512) so scores are in exp2 domain
    const float scl = (z == 0) ? 0.0637587238f : 1.0f;
#pragma unroll
    for (int ni = 0; ni < 4; ++ni) {
      int cc = n0 + ni * 16 + c;
      float bb = bias[cc];
#pragma unroll
      for (int mi = 0; mi < 4; ++mi)
#pragma unroll
        for (int r = 0; r < 4; ++r) {
          int row = m0 + mi * 16 + g * 4 + r;
          outp[(size_t)row * D_ + cc] = f2bf((acc[mi][ni][r] + bb) * scl);
        }
    }
  } else {
#pragma unroll
    for (int ni = 0; ni < 4; ++ni) {
      int e = n0 + ni * 16 + c;
      float bb = biasv[e];
#pragma unroll
      for (int mi = 0; mi < 4; ++mi) {
        int row = m0 + mi * 16 + g * 4;       // 4 consecutive s for r=0..3
        int bi = row >> 11, sl = row & 2047;
        int t = sl >> 5, kvin = sl & 31;      // kvin 4-aligned
        union { unsigned short u[4]; uint2 v; } pk;
#pragma unroll
        for (int r = 0; r < 4; ++r) pk.u[r] = f2bf(acc[mi][ni][r] + bb);
        *(uint2*)(Vs + ((((size_t)bi * 64 + t) * 512) + e) * 32 + kvin) = pk.v;
      }
    }
  }
}

// ---------------- stage 2a: P = exp2(S' - 8*log2e), l = row-sums ------------
// T4 port of the R20 k_pb schedule: SWAPPED operands (A = K rows -> m=kv,
// B = Q rows -> n=q), 256kv x 128q tile, 512 thr, 1 block/CU, triple-buffer
// counted-vmcnt pipeline (8 K-tiles of BK=64, 6 stages/thread/tile,
// vmcnt(6)+barrier at top-of-tile, stage t+2 mid-tile, no tail barrier).
// Epilogue: exp2 + cvt_pk + LDS-transpose pack (sm reused) -> 1KB stores,
// l row-sums via 2 shfl + atomics.
__global__ __launch_bounds__(512, 1) void k_pa(
    const unsigned short* __restrict__ Qb, const unsigned short* __restrict__ Kb,
    unsigned short* __restrict__ P, float* __restrict__ l,
    int b_base, int bc) {
  __shared__ __align__(16) unsigned char sm[147456];  // 3 x {A 32KB + B 16KB}
  const int lane = threadIdx.x & 63, wid = threadIdx.x >> 6;  // wid 0..7
  const int c = lane & 15, g = lane >> 4;
  const int wm = wid >> 2, wn = wid & 3;    // wm: kv-half(128), wn: q-quarter(32)
  const int bloc = blockIdx.x % bc;
  const int tile = blockIdx.x / bc;         // 0..127
  const int b = b_base + bloc;
  const int m_blk = (tile & 7) * 256;       // kv
  const int n_blk = (tile >> 3) * 128;      // q
  unsigned short* Pb = P + (size_t)bloc * S_ * S_;

  const int src_sw = ((lane & 7) * 16) ^ (((lane >> 3) & 7) << 4);
  // A = K rows (1024B stride): addr(t,row) = gA0 + row*1024 + t*128
  const unsigned char* gA0 = (const unsigned char*)(Kb + (size_t)b * S_ * D_)
      + (size_t)(m_blk + (lane >> 3)) * 1024 + src_sw;
  // B = Q rows (1024B stride)
  const unsigned char* gB0 = (const unsigned char*)(Qb + (size_t)b * S_ * D_)
      + (size_t)(n_blk + (lane >> 3)) * 1024 + src_sw;

  // stage A-half h_ (128 rows) of K-tile t_ into buffer bp_: 2 gl_lds/wave
#define STG_A(h_, t_, bp_)                                                   \
  {                                                                          \
    _Pragma("unroll")                                                        \
    for (int i = 0; i < 2; ++i) {                                            \
      int r0 = (h_) * 128 + wid * 16 + i * 8;                                \
      gl_lds16(gA0 + (size_t)r0 * 1024 + (t_) * 128,                         \
               sm + (bp_) * 49152 + r0 * 128);                               \
    }                                                                        \
  }
  // stage B-half h_ (64 rows) of K-tile t_: 1 gl_lds/wave
#define STG_B(h_, t_, bp_)                                                   \
  {                                                                          \
    int r0 = (h_) * 64 + wid * 8;                                            \
    gl_lds16(gB0 + (size_t)r0 * 1024 + (t_) * 128,                           \
             sm + (bp_) * 49152 + 32768 + r0 * 128);                         \
  }

  f32x4 acc[8][2];
#pragma unroll
  for (int a = 0; a < 8; ++a)
#pragma unroll
    for (int ni = 0; ni < 2; ++ni) acc[a][ni] = (f32x4){0.f, 0.f, 0.f, 0.f};

  // prologue: tiles 0 and 1 into buffers 0 and 1 (6 stages/thread each)
  STG_A(0, 0, 0); STG_B(0, 0, 0); STG_A(1, 0, 0); STG_B(1, 0, 0);
  STG_A(0, 1, 1); STG_B(0, 1, 1); STG_A(1, 1, 1); STG_B(1, 1, 1);

  for (int t = 0; t < 8; ++t) {
    const int cb = t % 3;
    const int nb = (t + 2) % 3;
    if (t < 7) asm volatile("s_waitcnt vmcnt(6)" ::: "memory");
    else       asm volatile("s_waitcnt vmcnt(0)" ::: "memory");
    __builtin_amdgcn_s_barrier();           // all waves' tile-t stages landed
    const unsigned char* Ab = sm + cb * 49152;
    const unsigned char* Bb = Ab + 32768;
    short8 bfr[2][2];
#pragma unroll
    for (int ni = 0; ni < 2; ++ni) {
      int row = wn * 32 + ni * 16 + c;
#pragma unroll
      for (int kc = 0; kc < 2; ++kc)
        bfr[ni][kc] = *(const short8*)(Bb + row * 128 + ((kc * 64 + g * 16) ^ ((c & 7) << 4)));
    }
    // ---- half-phase 0 (kv-quarter 0 of wave's half) ----
    {
      short8 af[4][2];
#pragma unroll
      for (int mi = 0; mi < 4; ++mi) {
        int row = wm * 128 + mi * 16 + c;
#pragma unroll
        for (int kc = 0; kc < 2; ++kc)
          af[mi][kc] = *(const short8*)(Ab + row * 128 + ((kc * 64 + g * 16) ^ ((c & 7) << 4)));
      }
      if (t < 6) { STG_A(0, t + 2, nb); STG_B(0, t + 2, nb); }
      __builtin_amdgcn_s_setprio(1);
#pragma unroll
      for (int kc = 0; kc < 2; ++kc)
#pragma unroll
        for (int mi = 0; mi < 4; ++mi)
#pragma unroll
          for (int ni = 0; ni < 2; ++ni)
            acc[mi][ni] = __builtin_amdgcn_mfma_f32_16x16x32_bf16(af[mi][kc], bfr[ni][kc], acc[mi][ni], 0, 0, 0);
      __builtin_amdgcn_s_setprio(0);
    }
    // ---- half-phase 1 ----
    {
      short8 af[4][2];
#pragma unroll
      for (int mi = 0; mi < 4; ++mi) {
        int row = wm * 128 + 64 + mi * 16 + c;
#pragma unroll
        for (int kc = 0; kc < 2; ++kc)
          af[mi][kc] = *(const short8*)(Ab + row * 128 + ((kc * 64 + g * 16) ^ ((c & 7) << 4)));
      }
      if (t < 6) { STG_A(1, t + 2, nb); STG_B(1, t + 2, nb); }
      __builtin_amdgcn_s_setprio(1);
#pragma unroll
      for (int kc = 0; kc < 2; ++kc)
#pragma unroll
        for (int mi = 0; mi < 4; ++mi)
#pragma unroll
          for (int ni = 0; ni < 2; ++ni)
            acc[4 + mi][ni] = __builtin_amdgcn_mfma_f32_16x16x32_bf16(af[mi][kc], bfr[ni][kc], acc[4 + mi][ni], 0, 0, 0);
      __builtin_amdgcn_s_setprio(0);
    }
    // no end-of-tile barrier: next tile's vmcnt+barrier provides ordering
  }
#undef STG_A
#undef STG_B

  // ---- epilogue ----
  __syncthreads();                          // all frag reads done; sm reusable
  const float SH = 11.5415603f;             // 8*log2(e)
  float psum[2] = {0.f, 0.f};
  // pack [128 q][512B kv] into sm, XOR-swizzled
#pragma unroll
  for (int ni = 0; ni < 2; ++ni) {
    const int q_loc = wn * 32 + ni * 16 + c;
#pragma unroll
    for (int a = 0; a < 8; ++a) {
      float p0 = fexp2(acc[a][ni][0] - SH);
      float p1 = fexp2(acc[a][ni][1] - SH);
      float p2 = fexp2(acc[a][ni][2] - SH);
      float p3 = fexp2(acc[a][ni][3] - SH);
      psum[ni] += (p0 + p1) + (p2 + p3);
      unsigned w0, w1;
      asm("v_cvt_pk_bf16_f32 %0, %1, %2" : "=v"(w0) : "v"(p0), "v"(p1));
      asm("v_cvt_pk_bf16_f32 %0, %1, %2" : "=v"(w1) : "v"(p2), "v"(p3));
      const int kv2 = wm * 256 + (a >> 2) * 128 + (a & 3) * 32 + g * 8;  // bytes
      *(uint2*)(sm + q_loc * 512 + (kv2 ^ ((q_loc & 15) << 4))) = (uint2){w0, w1};
    }
  }
#pragma unroll
  for (int ni = 0; ni < 2; ++ni) {
    float v = psum[ni];
    v += __shfl_xor(v, 16);
    v += __shfl_xor(v, 32);
    if (g == 0)
      atomicAdd(l + b * S_ + n_blk + wn * 32 + ni * 16 + c, v);
  }
  __syncthreads();                          // packed tile visible
  // coalesced store: wave wid covers q rows wid*16..+15; 2 rows (1KB) / instr
#pragma unroll
  for (int i = 0; i < 8; ++i) {
    const int q_loc = wid * 16 + i * 2 + (lane >> 5);
    const int kvb = (lane & 31) * 16;
    uint4 v = *(const uint4*)(sm + q_loc * 512 + (kvb ^ ((q_loc & 15) << 4)));
    *(uint4*)((unsigned char*)Pb + (size_t)(n_blk + q_loc) * 4096 + m_blk * 2 + kvb) = v;
  }
}

// ---------------- stage 2b: O = (P V) / l, computed as O^T ------------------
// Triple-buffered counted-vmcnt pipeline (T3+T4), verified R20.
__global__ __launch_bounds__(512, 1) void k_pb(
    const unsigned short* __restrict__ P, const unsigned short* __restrict__ Vs,
    const float* __restrict__ l, float* __restrict__ out,
    int b_base, int bc) {
  __shared__ __align__(16) unsigned char sm[147456];  // 3 x {A 32KB + B 16KB}
  const int lane = threadIdx.x & 63, wid = threadIdx.x >> 6;  // wid 0..7
  const int c = lane & 15, g = lane >> 4;
  const int wm = wid >> 2, wn = wid & 3;    // wm: d-half(128), wn: q-quarter(32)
  const int bloc = blockIdx.x % bc;
  const int tile = blockIdx.x / bc;         // 0..31
  const int b = b_base + bloc;
  const int m_blk = (tile & 1) * 256;       // d
  const int n_blk = (tile >> 1) * 128;      // q
  const unsigned char* Pb = (const unsigned char*)(P + (size_t)bloc * S_ * S_);
  const unsigned char* Vsb = (const unsigned char*)(Vs + (size_t)b * 64 * 512 * 32);

  const int src_sw = ((lane & 7) * 16) ^ (((lane >> 3) & 7) << 4);
  const unsigned char* gA0 = Vsb + (size_t)(src_sw >> 6) * 32768
      + (size_t)(m_blk + (lane >> 3)) * 64 + (src_sw & 63);
  const unsigned char* gB0 = Pb + (size_t)(n_blk + (lane >> 3)) * 4096 + src_sw;

#define STG_A(h_, t_, bp_)                                                   \
  {                                                                          \
    _Pragma("unroll")                                                        \
    for (int i = 0; i < 2; ++i) {                                            \
      int rl = wid * 16 + i * 8;                                             \
      int pbv = (rl & 63) + ((rl & 64) << 1) + (h_) * 64;                    \
      gl_lds16(gA0 + (size_t)(t_) * 65536 + (size_t)pbv * 64,                \
               sm + (bp_) * 49152 + pbv * 128);                              \
    }                                                                        \
  }
#define STG_B(h_, t_, bp_)                                                   \
  {                                                                          \
    int rl = wid * 8;                                                        \
    int pbv = (rl & 8) + (h_) * 16 + ((rl >> 4) << 5);                       \
    gl_lds16(gB0 + (size_t)pbv * 4096 + (t_) * 128,                          \
             sm + (bp_) * 49152 + 32768 + pbv * 128);                        \
  }

  f32x4 acc[8][2];
#pragma unroll
  for (int a = 0; a < 8; ++a)
#pragma unroll
    for (int ni = 0; ni < 2; ++ni) acc[a][ni] = (f32x4){0.f, 0.f, 0.f, 0.f};

  STG_A(0, 0, 0); STG_B(0, 0, 0); STG_A(1, 0, 0); STG_B(1, 0, 0);
  STG_A(0, 1, 1); STG_B(0, 1, 1); STG_A(1, 1, 1); STG_B(1, 1, 1);

  for (int t = 0; t < 32; ++t) {
    const int cb = t % 3;
    const int nb = (t + 2) % 3;
    if (t < 31) asm volatile("s_waitcnt vmcnt(6)" ::: "memory");
    else        asm volatile("s_waitcnt vmcnt(0)" ::: "memory");
    __builtin_amdgcn_s_barrier();
    const unsigned char* Ab = sm + cb * 49152;
    const unsigned char* Bb = Ab + 32768;
    short8 bfr[2][2];
#pragma unroll
    for (int ni = 0; ni < 2; ++ni) {
      int row = wn * 32 + ni * 16 + c;
#pragma unroll
      for (int kc = 0; kc < 2; ++kc)
        bfr[ni][kc] = *(const short8*)(Bb + row * 128 + ((kc * 64 + g * 16) ^ ((c & 7) << 4)));
    }
    {
      short8 af[4][2];
#pragma unroll
      for (int mi = 0; mi < 4; ++mi) {
        int row = wm * 128 + mi * 16 + c;
#pragma unroll
        for (int kc = 0; kc < 2; ++kc)
          af[mi][kc] = *(const short8*)(Ab + row * 128 + ((kc * 64 + g * 16) ^ ((c & 7) << 4)));
      }
      if (t < 30) { STG_A(0, t + 2, nb); STG_B(0, t + 2, nb); }
      __builtin_amdgcn_s_setprio(1);
#pragma unroll
      for (int kc = 0; kc < 2; ++kc)
#pragma unroll
        for (int mi = 0; mi < 4; ++mi)
#pragma unroll
          for (int ni = 0; ni < 2; ++ni)
            acc[mi][ni] = __builtin_amdgcn_mfma_f32_16x16x32_bf16(af[mi][kc], bfr[ni][kc], acc[mi][ni], 0, 0, 0);
      __builtin_amdgcn_s_setprio(0);
    }
    {
      short8 af[4][2];
#pragma unroll
      for (int mi = 0; mi < 4; ++mi) {
        int row = wm * 128 + 64 + mi * 16 + c;
#pragma unroll
        for (int kc = 0; kc < 2; ++kc)
          af[mi][kc] = *(const short8*)(Ab + row * 128 + ((kc * 64 + g * 16) ^ ((c & 7) << 4)));
      }
      if (t < 30) { STG_A(1, t + 2, nb); STG_B(1, t + 2, nb); }
      __builtin_amdgcn_s_setprio(1);
#pragma unroll
      for (int kc = 0; kc < 2; ++kc)
#pragma unroll
        for (int mi = 0; mi < 4; ++mi)
#pragma unroll
          for (int ni = 0; ni < 2; ++ni)
            acc[4 + mi][ni] = __builtin_amdgcn_mfma_f32_16x16x32_bf16(af[mi][kc], bfr[ni][kc], acc[4 + mi][ni], 0, 0, 0);
      __builtin_amdgcn_s_setprio(0);
    }
  }
#undef STG_A
#undef STG_B

  float* ob = out + (size_t)b * S_ * D_;
#pragma unroll
  for (int ni = 0; ni < 2; ++ni) {
    const int q = n_blk + wn * 32 + ni * 16 + c;
    const float inv = 1.f / l[b * S_ + q];
#pragma unroll
    for (int a = 0; a < 8; ++a) {
      const int d0 = m_blk + wm * 128 + (a >> 2) * 64 + (a & 3) * 16 + g * 4;
      float4 v;
      v.x = acc[a][ni][0] * inv; v.y = acc[a][ni][1] * inv;
      v.z = acc[a][ni][2] * inv; v.w = acc[a][ni][3] * inv;
      *(float4*)(ob + (size_t)q * D_ + d0) = v;
    }
  }
}

// ---------------- launch ----------------------------------------------------
extern "C" void kernel_launch(void* const* d_in, const int* in_sizes, int n_in,
                              void* d_out, int out_size, void* d_ws, size_t ws_size,
                              hipStream_t stream) {
  const float* x  = (const float*)d_in[0];
  const float* Wq = (const float*)d_in[1];
  const float* bq = (const float*)d_in[2];
  const float* Wk = (const float*)d_in[3];
  const float* bk = (const float*)d_in[4];
  const float* Wv = (const float*)d_in[5];
  const float* bv = (const float*)d_in[6];
  float* out = (float*)d_out;

  // workspace layout (bf16 unless noted)
  unsigned short* xb = (unsigned short*)d_ws;              // [16384][512]  (dead after k_qkv)
  unsigned short* Wt = xb + (size_t)16384 * 512;           // [3][512][512] (dead after k_qkv)
  unsigned short* Qb = Wt + (size_t)3 * 512 * 512;         // [16384][512], pre-scaled
  unsigned short* Kb = Qb + (size_t)16384 * 512;           // [16384][512]
  unsigned short* Vs = Kb + (size_t)16384 * 512;           // [8][64][512][32] tile-major
  float* l = (float*)(Vs + (size_t)8 * 64 * 512 * 32);     // [8][2048] f32 — OWN slot
  unsigned short* Pfull = (unsigned short*)(l + 8 * 2048); // [8][2048][2048] (if ws allows)
  const size_t full_need =
      (size_t)((unsigned char*)(Pfull + (size_t)8 * 2048 * 2048) - (unsigned char*)d_ws);

  k_prep<<<dim3(7232), dim3(256), 0, stream>>>(x, Wq, Wk, Wv, xb, Wt, l);
  k_qkv<<<dim3(128, 4, 3), dim3(256), 0, stream>>>(xb, Wt, bq, bk, bv, Qb, Kb, Vs);

  if (ws_size >= full_need) {
    k_pa<<<dim3(1024), dim3(512), 0, stream>>>(Qb, Kb, Pfull, l, 0, 8);
    k_pb<<<dim3(256),  dim3(512), 0, stream>>>(Pfull, Vs, l, out, 0, 8);
  } else {
    // 2 batches of P fit exactly in the dead xb region (16.7 MB).
    unsigned short* P2 = xb;
    for (int g2 = 0; g2 < 4; ++g2) {
      k_pa<<<dim3(256), dim3(512), 0, stream>>>(Qb, Kb, P2, l, g2 * 2, 2);
      k_pb<<<dim3(64), dim3(512), 0, stream>>>(P2, Vs, l, out, g2 * 2, 2);
    }
  }
}

// Round 22
// 119.536 us; speedup vs baseline: 1.0326x; 1.0326x over previous
//
#include <hip/hip_runtime.h>
#include <hip/hip_bf16.h>

#define B_ 8
#define S_ 2048
#define D_ 512

typedef __attribute__((ext_vector_type(8))) short short8;
typedef __attribute__((ext_vector_type(4))) float f32x4;

static __device__ __forceinline__ unsigned short f2bf(float f) {
    union { float f; unsigned u; } v; v.f = f;
    unsigned r = v.u + 0x7FFFu + ((v.u >> 16) & 1u);   // round-nearest-even
    return (unsigned short)(r >> 16);
}

static __device__ __forceinline__ float fexp2(float x) {   // 2^x, native
    float r; asm("v_exp_f32 %0, %1" : "=v"(r) : "v"(x)); return r;
}

static __device__ __forceinline__ void gl_lds16(const void* g, void* l) {
    __builtin_amdgcn_global_load_lds(
        (const __attribute__((address_space(1))) unsigned int*)g,
        (__attribute__((address_space(3))) unsigned int*)l, 16, 0, 0);
}

// ---------------- stage 0 (fused): x->bf16, W->bf16^T, l=0 ------------------
__global__ void k_prep(const float* __restrict__ x,
                       const float* __restrict__ Wq, const float* __restrict__ Wk,
                       const float* __restrict__ Wv,
                       unsigned short* __restrict__ xb, unsigned short* __restrict__ Wt,
                       float* __restrict__ l) {
    int bid = blockIdx.x;
    if (bid < 4096) {
        int i = bid * 256 + threadIdx.x;             // one thread per 8 elems
        const float4* p = (const float4*)x + (size_t)i * 2;
        float4 a = p[0], b = p[1];
        union { unsigned short u[8]; uint4 v; } o;
        o.u[0] = f2bf(a.x); o.u[1] = f2bf(a.y); o.u[2] = f2bf(a.z); o.u[3] = f2bf(a.w);
        o.u[4] = f2bf(b.x); o.u[5] = f2bf(b.y); o.u[6] = f2bf(b.z); o.u[7] = f2bf(b.w);
        ((uint4*)xb)[i] = o.v;
    } else if (bid < 7168) {
        int idx = (bid - 4096) * 256 + threadIdx.x;  // 0 .. 3*512*512-1
        int z = idx >> 18;
        int r = idx & 262143;
        int e = r >> 9, d = r & 511;
        const float* W = (z == 0) ? Wq : ((z == 1) ? Wk : Wv);
        Wt[idx] = f2bf(W[d * 512 + e]);
    } else {
        l[(bid - 7168) * 256 + threadIdx.x] = 0.f;
    }
}

// ---------------- stage 1: QKV projection GEMM (LDS-staged, 128x128) --------
__global__ __launch_bounds__(256, 4) void k_qkv(
    const unsigned short* __restrict__ xb, const unsigned short* __restrict__ Wt,
    const float* __restrict__ biasq, const float* __restrict__ biask,
    const float* __restrict__ biasv,
    unsigned short* __restrict__ Qb, unsigned short* __restrict__ Kb,
    unsigned short* __restrict__ Vs) {
  __shared__ __align__(16) unsigned char smA[16384];   // A tile [128 m][64 k], swz
  __shared__ __align__(16) unsigned char smB[16384];   // B tile [128 n][64 k], swz
  const int z = blockIdx.z;
  const unsigned short* W = Wt + (size_t)z * (D_ * D_);
  const int lane = threadIdx.x & 63, wid = threadIdx.x >> 6;
  const int c = lane & 15, g = lane >> 4;
  const int wr = wid >> 1, wc = wid & 1;
  const int m_blk = blockIdx.x * 128;
  const int n_blk = blockIdx.y * 128;

  const int src_sw = ((lane & 7) * 16) ^ (((lane >> 3) & 7) << 4);
  const unsigned char* ga = (const unsigned char*)xb
      + (size_t)(m_blk + wid * 32 + (lane >> 3)) * 1024;
  const unsigned char* gb = (const unsigned char*)W
      + (size_t)(n_blk + wid * 32 + (lane >> 3)) * 1024;
  unsigned char* la = smA + wid * 4096;
  unsigned char* lb = smB + wid * 4096;

  f32x4 acc[4][4];
#pragma unroll
  for (int mi = 0; mi < 4; ++mi)
#pragma unroll
    for (int ni = 0; ni < 4; ++ni) acc[mi][ni] = (f32x4){0.f, 0.f, 0.f, 0.f};

  for (int step = 0; step < 8; ++step) {
    __syncthreads();                                  // prev-tile reads done
#pragma unroll
    for (int i = 0; i < 4; ++i) {
      gl_lds16(ga + (size_t)i * 8192 + step * 128 + src_sw, la + i * 1024);
      gl_lds16(gb + (size_t)i * 8192 + step * 128 + src_sw, lb + i * 1024);
    }
    __syncthreads();                                  // staged data visible
#pragma unroll
    for (int kc = 0; kc < 2; ++kc) {
      const int ro = (kc * 64 + g * 16) ^ ((c & 7) << 4);
      short8 af[4], bf[4];
#pragma unroll
      for (int mi = 0; mi < 4; ++mi)
        af[mi] = *(const short8*)(smA + (wr * 64 + mi * 16 + c) * 128 + ro);
#pragma unroll
      for (int ni = 0; ni < 4; ++ni)
        bf[ni] = *(const short8*)(smB + (wc * 64 + ni * 16 + c) * 128 + ro);
#pragma unroll
      for (int mi = 0; mi < 4; ++mi)
#pragma unroll
        for (int ni = 0; ni < 4; ++ni)
          acc[mi][ni] = __builtin_amdgcn_mfma_f32_16x16x32_bf16(af[mi], bf[ni], acc[mi][ni], 0, 0, 0);
    }
  }

  const int m0 = m_blk + wr * 64;
  const int n0 = n_blk + wc * 64;
  if (z < 2) {
    const float* bias = (z == 0) ? biasq : biask;
    unsigned short* outp = (z == 0) ? Qb : Kb;
    // z=0: log2(e)/sqrt(512) so scores are in exp2 domain
    const float scl = (z == 0) ? 0.0637587238f : 1.0f;
#pragma unroll
    for (int ni = 0; ni < 4; ++ni) {
      int cc = n0 + ni * 16 + c;
      float bb = bias[cc];
#pragma unroll
      for (int mi = 0; mi < 4; ++mi)
#pragma unroll
        for (int r = 0; r < 4; ++r) {
          int row = m0 + mi * 16 + g * 4 + r;
          outp[(size_t)row * D_ + cc] = f2bf((acc[mi][ni][r] + bb) * scl);
        }
    }
  } else {
#pragma unroll
    for (int ni = 0; ni < 4; ++ni) {
      int e = n0 + ni * 16 + c;
      float bb = biasv[e];
#pragma unroll
      for (int mi = 0; mi < 4; ++mi) {
        int row = m0 + mi * 16 + g * 4;       // 4 consecutive s for r=0..3
        int bi = row >> 11, sl = row & 2047;
        int t = sl >> 5, kvin = sl & 31;      // kvin 4-aligned
        union { unsigned short u[4]; uint2 v; } pk;
#pragma unroll
        for (int r = 0; r < 4; ++r) pk.u[r] = f2bf(acc[mi][ni][r] + bb);
        *(uint2*)(Vs + ((((size_t)bi * 64 + t) * 512) + e) * 32 + kvin) = pk.v;
      }
    }
  }
}

// ---------------- stage 2a: P = exp2(S' - 8*log2e), l = row-sums ------------
// SWAPPED operands: C = S^T (m=kv, n=q). 128x128, single-buffer 2-barrier,
// 256 thr, 4 blocks/CU (inter-block overlap covers epilogue — R21 lesson:
// T4 pipeline loses here at K=512 / 8 tiles). Epilogue packs bf16 P through
// LDS -> 8 coalesced uint4 stores.
__global__ __launch_bounds__(256, 4) void k_pa(
    const unsigned short* __restrict__ Qb, const unsigned short* __restrict__ Kb,
    unsigned short* __restrict__ P, float* __restrict__ l,
    int b_base, int bc) {
  __shared__ __align__(16) unsigned char smA[16384];
  __shared__ __align__(16) unsigned char smB[16384];
  const int lane = threadIdx.x & 63, wid = threadIdx.x >> 6;
  const int c = lane & 15, g = lane >> 4;
  const int wr = wid >> 1, wc = wid & 1;
  const int bloc = blockIdx.x % bc;
  const int tile = blockIdx.x / bc;
  const int b = b_base + bloc;
  const int m_blk = (tile & 15) * 128;      // kv
  const int n_blk = (tile >> 4) * 128;      // q
  unsigned short* Pb = P + (size_t)bloc * S_ * S_;

  const int src_sw = ((lane & 7) * 16) ^ (((lane >> 3) & 7) << 4);
  const unsigned char* ga = (const unsigned char*)(Kb + (size_t)b * S_ * D_)
      + (size_t)(m_blk + wid * 32 + (lane >> 3)) * 1024;   // A = K rows
  const unsigned char* gb = (const unsigned char*)(Qb + (size_t)b * S_ * D_)
      + (size_t)(n_blk + wid * 32 + (lane >> 3)) * 1024;   // B = Q rows
  unsigned char* la = smA + wid * 4096;
  unsigned char* lb = smB + wid * 4096;

  f32x4 acc[4][4];
#pragma unroll
  for (int mi = 0; mi < 4; ++mi)
#pragma unroll
    for (int ni = 0; ni < 4; ++ni) acc[mi][ni] = (f32x4){0.f, 0.f, 0.f, 0.f};

  for (int step = 0; step < 8; ++step) {
    __syncthreads();
#pragma unroll
    for (int i = 0; i < 4; ++i) {
      gl_lds16(ga + (size_t)i * 8192 + step * 128 + src_sw, la + i * 1024);
      gl_lds16(gb + (size_t)i * 8192 + step * 128 + src_sw, lb + i * 1024);
    }
    __syncthreads();
#pragma unroll
    for (int kc = 0; kc < 2; ++kc) {
      const int ro = (kc * 64 + g * 16) ^ ((c & 7) << 4);
      short8 af[4], bf[4];
#pragma unroll
      for (int mi = 0; mi < 4; ++mi)
        af[mi] = *(const short8*)(smA + (wr * 64 + mi * 16 + c) * 128 + ro);
#pragma unroll
      for (int ni = 0; ni < 4; ++ni)
        bf[ni] = *(const short8*)(smB + (wc * 64 + ni * 16 + c) * 128 + ro);
#pragma unroll
      for (int mi = 0; mi < 4; ++mi)
#pragma unroll
        for (int ni = 0; ni < 4; ++ni)
          acc[mi][ni] = __builtin_amdgcn_mfma_f32_16x16x32_bf16(af[mi], bf[ni], acc[mi][ni], 0, 0, 0);
    }
  }

  const float SH = 11.5415603f;             // 8*log2(e)
  float psum[4] = {0.f, 0.f, 0.f, 0.f};
  __syncthreads();                          // K-loop LDS reads done; smA free
#pragma unroll
  for (int ni = 0; ni < 4; ++ni) {
    const int q_loc = wc * 64 + ni * 16 + c;
#pragma unroll
    for (int mi = 0; mi < 4; ++mi) {
      float p0 = fexp2(acc[mi][ni][0] - SH);
      float p1 = fexp2(acc[mi][ni][1] - SH);
      float p2 = fexp2(acc[mi][ni][2] - SH);
      float p3 = fexp2(acc[mi][ni][3] - SH);
      psum[ni] += (p0 + p1) + (p2 + p3);
      unsigned w0, w1;
      asm("v_cvt_pk_bf16_f32 %0, %1, %2" : "=v"(w0) : "v"(p0), "v"(p1));
      asm("v_cvt_pk_bf16_f32 %0, %1, %2" : "=v"(w1) : "v"(p2), "v"(p3));
      const int kv2 = (wr * 64 + mi * 16 + g * 4) * 2;
      *(uint2*)(smA + q_loc * 256 + (kv2 ^ ((q_loc & 15) << 4))) = (uint2){w0, w1};
    }
  }
#pragma unroll
  for (int ni = 0; ni < 4; ++ni) {
    float v = psum[ni];
    v += __shfl_xor(v, 16);
    v += __shfl_xor(v, 32);
    if (g == 0)
      atomicAdd(l + b * S_ + n_blk + wc * 64 + ni * 16 + c, v);
  }
  __syncthreads();                          // packed tile visible
#pragma unroll
  for (int i = 0; i < 8; ++i) {
    const int q_loc = wid * 32 + i * 4 + (lane >> 4);
    const int kvb = (lane & 15) * 16;
    uint4 v = *(const uint4*)(smA + q_loc * 256 + (kvb ^ ((q_loc & 15) << 4)));
    *(uint4*)((unsigned char*)Pb + (size_t)(n_blk + q_loc) * 4096 + m_blk * 2 + kvb) = v;
  }
}

// ---------------- stage 2b: O = (P V) / l, computed as O^T ------------------
// Triple-buffered counted-vmcnt pipeline (T3+T4), verified R20 (+2.5 µs win;
// works here because K=2048 = 32 tiles amortizes the 2-tile prologue).
__global__ __launch_bounds__(512, 1) void k_pb(
    const unsigned short* __restrict__ P, const unsigned short* __restrict__ Vs,
    const float* __restrict__ l, float* __restrict__ out,
    int b_base, int bc) {
  __shared__ __align__(16) unsigned char sm[147456];  // 3 x {A 32KB + B 16KB}
  const int lane = threadIdx.x & 63, wid = threadIdx.x >> 6;  // wid 0..7
  const int c = lane & 15, g = lane >> 4;
  const int wm = wid >> 2, wn = wid & 3;    // wm: d-half(128), wn: q-quarter(32)
  const int bloc = blockIdx.x % bc;
  const int tile = blockIdx.x / bc;         // 0..31
  const int b = b_base + bloc;
  const int m_blk = (tile & 1) * 256;       // d
  const int n_blk = (tile >> 1) * 128;      // q
  const unsigned char* Pb = (const unsigned char*)(P + (size_t)bloc * S_ * S_);
  const unsigned char* Vsb = (const unsigned char*)(Vs + (size_t)b * 64 * 512 * 32);

  const int src_sw = ((lane & 7) * 16) ^ (((lane >> 3) & 7) << 4);
  const unsigned char* gA0 = Vsb + (size_t)(src_sw >> 6) * 32768
      + (size_t)(m_blk + (lane >> 3)) * 64 + (src_sw & 63);
  const unsigned char* gB0 = Pb + (size_t)(n_blk + (lane >> 3)) * 4096 + src_sw;

#define STG_A(h_, t_, bp_)                                                   \
  {                                                                          \
    _Pragma("unroll")                                                        \
    for (int i = 0; i < 2; ++i) {                                            \
      int rl = wid * 16 + i * 8;                                             \
      int pbv = (rl & 63) + ((rl & 64) << 1) + (h_) * 64;                    \
      gl_lds16(gA0 + (size_t)(t_) * 65536 + (size_t)pbv * 64,                \
               sm + (bp_) * 49152 + pbv * 128);                              \
    }                                                                        \
  }
#define STG_B(h_, t_, bp_)                                                   \
  {                                                                          \
    int rl = wid * 8;                                                        \
    int pbv = (rl & 8) + (h_) * 16 + ((rl >> 4) << 5);                       \
    gl_lds16(gB0 + (size_t)pbv * 4096 + (t_) * 128,                          \
             sm + (bp_) * 49152 + 32768 + pbv * 128);                        \
  }

  f32x4 acc[8][2];
#pragma unroll
  for (int a = 0; a < 8; ++a)
#pragma unroll
    for (int ni = 0; ni < 2; ++ni) acc[a][ni] = (f32x4){0.f, 0.f, 0.f, 0.f};

  STG_A(0, 0, 0); STG_B(0, 0, 0); STG_A(1, 0, 0); STG_B(1, 0, 0);
  STG_A(0, 1, 1); STG_B(0, 1, 1); STG_A(1, 1, 1); STG_B(1, 1, 1);

  for (int t = 0; t < 32; ++t) {
    const int cb = t % 3;
    const int nb = (t + 2) % 3;
    if (t < 31) asm volatile("s_waitcnt vmcnt(6)" ::: "memory");
    else        asm volatile("s_waitcnt vmcnt(0)" ::: "memory");
    __builtin_amdgcn_s_barrier();
    const unsigned char* Ab = sm + cb * 49152;
    const unsigned char* Bb = Ab + 32768;
    short8 bfr[2][2];
#pragma unroll
    for (int ni = 0; ni < 2; ++ni) {
      int row = wn * 32 + ni * 16 + c;
#pragma unroll
      for (int kc = 0; kc < 2; ++kc)
        bfr[ni][kc] = *(const short8*)(Bb + row * 128 + ((kc * 64 + g * 16) ^ ((c & 7) << 4)));
    }
    {
      short8 af[4][2];
#pragma unroll
      for (int mi = 0; mi < 4; ++mi) {
        int row = wm * 128 + mi * 16 + c;
#pragma unroll
        for (int kc = 0; kc < 2; ++kc)
          af[mi][kc] = *(const short8*)(Ab + row * 128 + ((kc * 64 + g * 16) ^ ((c & 7) << 4)));
      }
      if (t < 30) { STG_A(0, t + 2, nb); STG_B(0, t + 2, nb); }
      __builtin_amdgcn_s_setprio(1);
#pragma unroll
      for (int kc = 0; kc < 2; ++kc)
#pragma unroll
        for (int mi = 0; mi < 4; ++mi)
#pragma unroll
          for (int ni = 0; ni < 2; ++ni)
            acc[mi][ni] = __builtin_amdgcn_mfma_f32_16x16x32_bf16(af[mi][kc], bfr[ni][kc], acc[mi][ni], 0, 0, 0);
      __builtin_amdgcn_s_setprio(0);
    }
    {
      short8 af[4][2];
#pragma unroll
      for (int mi = 0; mi < 4; ++mi) {
        int row = wm * 128 + 64 + mi * 16 + c;
#pragma unroll
        for (int kc = 0; kc < 2; ++kc)
          af[mi][kc] = *(const short8*)(Ab + row * 128 + ((kc * 64 + g * 16) ^ ((c & 7) << 4)));
      }
      if (t < 30) { STG_A(1, t + 2, nb); STG_B(1, t + 2, nb); }
      __builtin_amdgcn_s_setprio(1);
#pragma unroll
      for (int kc = 0; kc < 2; ++kc)
#pragma unroll
        for (int mi = 0; mi < 4; ++mi)
#pragma unroll
          for (int ni = 0; ni < 2; ++ni)
            acc[4 + mi][ni] = __builtin_amdgcn_mfma_f32_16x16x32_bf16(af[mi][kc], bfr[ni][kc], acc[4 + mi][ni], 0, 0, 0);
      __builtin_amdgcn_s_setprio(0);
    }
  }
#undef STG_A
#undef STG_B

  float* ob = out + (size_t)b * S_ * D_;
#pragma unroll
  for (int ni = 0; ni < 2; ++ni) {
    const int q = n_blk + wn * 32 + ni * 16 + c;
    const float inv = 1.f / l[b * S_ + q];
#pragma unroll
    for (int a = 0; a < 8; ++a) {
      const int d0 = m_blk + wm * 128 + (a >> 2) * 64 + (a & 3) * 16 + g * 4;
      float4 v;
      v.x = acc[a][ni][0] * inv; v.y = acc[a][ni][1] * inv;
      v.z = acc[a][ni][2] * inv; v.w = acc[a][ni][3] * inv;
      *(float4*)(ob + (size_t)q * D_ + d0) = v;
    }
  }
}

// ---------------- launch ----------------------------------------------------
extern "C" void kernel_launch(void* const* d_in, const int* in_sizes, int n_in,
                              void* d_out, int out_size, void* d_ws, size_t ws_size,
                              hipStream_t stream) {
  const float* x  = (const float*)d_in[0];
  const float* Wq = (const float*)d_in[1];
  const float* bq = (const float*)d_in[2];
  const float* Wk = (const float*)d_in[3];
  const float* bk = (const float*)d_in[4];
  const float* Wv = (const float*)d_in[5];
  const float* bv = (const float*)d_in[6];
  float* out = (float*)d_out;

  // workspace layout (bf16 unless noted)
  unsigned short* xb = (unsigned short*)d_ws;              // [16384][512]  (dead after k_qkv)
  unsigned short* Wt = xb + (size_t)16384 * 512;           // [3][512][512] (dead after k_qkv)
  unsigned short* Qb = Wt + (size_t)3 * 512 * 512;         // [16384][512], pre-scaled
  unsigned short* Kb = Qb + (size_t)16384 * 512;           // [16384][512]
  unsigned short* Vs = Kb + (size_t)16384 * 512;           // [8][64][512][32] tile-major
  float* l = (float*)(Vs + (size_t)8 * 64 * 512 * 32);     // [8][2048] f32 — OWN slot
  unsigned short* Pfull = (unsigned short*)(l + 8 * 2048); // [8][2048][2048] (if ws allows)
  const size_t full_need =
      (size_t)((unsigned char*)(Pfull + (size_t)8 * 2048 * 2048) - (unsigned char*)d_ws);

  k_prep<<<dim3(7232), dim3(256), 0, stream>>>(x, Wq, Wk, Wv, xb, Wt, l);
  k_qkv<<<dim3(128, 4, 3), dim3(256), 0, stream>>>(xb, Wt, bq, bk, bv, Qb, Kb, Vs);

  if (ws_size >= full_need) {
    k_pa<<<dim3(2048), dim3(256), 0, stream>>>(Qb, Kb, Pfull, l, 0, 8);
    k_pb<<<dim3(256),  dim3(512), 0, stream>>>(Pfull, Vs, l, out, 0, 8);
  } else {
    // 2 batches of P fit exactly in the dead xb region (16.7 MB).
    unsigned short* P2 = xb;
    for (int g2 = 0; g2 < 4; ++g2) {
      k_pa<<<dim3(512), dim3(256), 0, stream>>>(Qb, Kb, P2, l, g2 * 2, 2);
      k_pb<<<dim3(64), dim3(512), 0, stream>>>(P2, Vs, l, out, g2 * 2, 2);
    }
  }
}

// Round 23
// 117.464 us; speedup vs baseline: 1.0508x; 1.0176x over previous
//
#include <hip/hip_runtime.h>
#include <hip/hip_bf16.h>

#define B_ 8
#define S_ 2048
#define D_ 512

typedef __attribute__((ext_vector_type(8))) short short8;
typedef __attribute__((ext_vector_type(4))) float f32x4;

static __device__ __forceinline__ unsigned short f2bf(float f) {
    union { float f; unsigned u; } v; v.f = f;
    unsigned r = v.u + 0x7FFFu + ((v.u >> 16) & 1u);   // round-nearest-even
    return (unsigned short)(r >> 16);
}

static __device__ __forceinline__ float fexp2(float x) {   // 2^x, native
    float r; asm("v_exp_f32 %0, %1" : "=v"(r) : "v"(x)); return r;
}

static __device__ __forceinline__ void gl_lds16(const void* g, void* l) {
    __builtin_amdgcn_global_load_lds(
        (const __attribute__((address_space(1))) unsigned int*)g,
        (__attribute__((address_space(3))) unsigned int*)l, 16, 0, 0);
}

// ---------------- stage 0 (fused): x->bf16, W->bf16^T, l=0 ------------------
__global__ void k_prep(const float* __restrict__ x,
                       const float* __restrict__ Wq, const float* __restrict__ Wk,
                       const float* __restrict__ Wv,
                       unsigned short* __restrict__ xb, unsigned short* __restrict__ Wt,
                       float* __restrict__ l) {
    int bid = blockIdx.x;
    if (bid < 4096) {
        int i = bid * 256 + threadIdx.x;             // one thread per 8 elems
        const float4* p = (const float4*)x + (size_t)i * 2;
        float4 a = p[0], b = p[1];
        union { unsigned short u[8]; uint4 v; } o;
        o.u[0] = f2bf(a.x); o.u[1] = f2bf(a.y); o.u[2] = f2bf(a.z); o.u[3] = f2bf(a.w);
        o.u[4] = f2bf(b.x); o.u[5] = f2bf(b.y); o.u[6] = f2bf(b.z); o.u[7] = f2bf(b.w);
        ((uint4*)xb)[i] = o.v;
    } else if (bid < 7168) {
        int idx = (bid - 4096) * 256 + threadIdx.x;  // 0 .. 3*512*512-1
        int z = idx >> 18;
        int r = idx & 262143;
        int e = r >> 9, d = r & 511;
        const float* W = (z == 0) ? Wq : ((z == 1) ? Wk : Wv);
        Wt[idx] = f2bf(W[d * 512 + e]);
    } else {
        l[(bid - 7168) * 256 + threadIdx.x] = 0.f;
    }
}

// ---------------- stage 1: QKV projection GEMM (LDS-staged, 128x128) --------
// z<2 (Q,K): SWAPPED operands (A = Wt rows -> m=d, B = xb rows -> n=s) so the
// acc quad spans 4 CONTIGUOUS d -> cvt_pk + LDS-pack + coalesced uint4 stores
// (verified k_pa-R15 pattern). z=2 (Vs): unswapped (quad spans contiguous s,
// already uint2 stores into tile-major Vs).
__global__ __launch_bounds__(256, 4) void k_qkv(
    const unsigned short* __restrict__ xb, const unsigned short* __restrict__ Wt,
    const float* __restrict__ biasq, const float* __restrict__ biask,
    const float* __restrict__ biasv,
    unsigned short* __restrict__ Qb, unsigned short* __restrict__ Kb,
    unsigned short* __restrict__ Vs) {
  __shared__ __align__(16) unsigned char sm[32768];    // A tile | B tile (swz)
  const int z = blockIdx.z;
  const unsigned short* W = Wt + (size_t)z * (D_ * D_);
  const int lane = threadIdx.x & 63, wid = threadIdx.x >> 6;
  const int c = lane & 15, g = lane >> 4;
  const int wr = wid >> 1, wc = wid & 1;
  const bool swp = (z < 2);
  // swapped: m = d (blockIdx.y, 4 tiles), n = s (blockIdx.x, 128 tiles)
  const int m_blk = swp ? blockIdx.y * 128 : blockIdx.x * 128;
  const int n_blk = swp ? blockIdx.x * 128 : blockIdx.y * 128;

  const int src_sw = ((lane & 7) * 16) ^ (((lane >> 3) & 7) << 4);
  const unsigned char* ga = (swp ? (const unsigned char*)W : (const unsigned char*)xb)
      + (size_t)(m_blk + wid * 32 + (lane >> 3)) * 1024;
  const unsigned char* gb = (swp ? (const unsigned char*)xb : (const unsigned char*)W)
      + (size_t)(n_blk + wid * 32 + (lane >> 3)) * 1024;
  unsigned char* la = sm + wid * 4096;
  unsigned char* lb = sm + 16384 + wid * 4096;

  f32x4 acc[4][4];
#pragma unroll
  for (int mi = 0; mi < 4; ++mi)
#pragma unroll
    for (int ni = 0; ni < 4; ++ni) acc[mi][ni] = (f32x4){0.f, 0.f, 0.f, 0.f};

  for (int step = 0; step < 8; ++step) {
    __syncthreads();                                  // prev-tile reads done
#pragma unroll
    for (int i = 0; i < 4; ++i) {
      gl_lds16(ga + (size_t)i * 8192 + step * 128 + src_sw, la + i * 1024);
      gl_lds16(gb + (size_t)i * 8192 + step * 128 + src_sw, lb + i * 1024);
    }
    __syncthreads();                                  // staged data visible
#pragma unroll
    for (int kc = 0; kc < 2; ++kc) {
      const int ro = (kc * 64 + g * 16) ^ ((c & 7) << 4);
      short8 af[4], bf[4];
#pragma unroll
      for (int mi = 0; mi < 4; ++mi)
        af[mi] = *(const short8*)(sm + (wr * 64 + mi * 16 + c) * 128 + ro);
#pragma unroll
      for (int ni = 0; ni < 4; ++ni)
        bf[ni] = *(const short8*)(sm + 16384 + (wc * 64 + ni * 16 + c) * 128 + ro);
#pragma unroll
      for (int mi = 0; mi < 4; ++mi)
#pragma unroll
        for (int ni = 0; ni < 4; ++ni)
          acc[mi][ni] = __builtin_amdgcn_mfma_f32_16x16x32_bf16(af[mi], bf[ni], acc[mi][ni], 0, 0, 0);
    }
  }

  if (swp) {
    // ---- Q/K epilogue: bias+scale, pack via LDS, coalesced uint4 stores ----
    const float* bias = (z == 0) ? biasq : biask;
    unsigned short* outp = (z == 0) ? Qb : Kb;
    // z=0: log2(e)/sqrt(512) so scores are in exp2 domain
    const float scl = (z == 0) ? 0.0637587238f : 1.0f;
    __syncthreads();                        // K-loop LDS reads done; sm free
#pragma unroll
    for (int mi = 0; mi < 4; ++mi) {
      const int d0 = m_blk + wr * 64 + mi * 16 + g * 4;   // 4 contiguous d
      const float4 bb = *(const float4*)(bias + d0);
#pragma unroll
      for (int ni = 0; ni < 4; ++ni) {
        const int s_loc = wc * 64 + ni * 16 + c;
        float v0 = (acc[mi][ni][0] + bb.x) * scl;
        float v1 = (acc[mi][ni][1] + bb.y) * scl;
        float v2 = (acc[mi][ni][2] + bb.z) * scl;
        float v3 = (acc[mi][ni][3] + bb.w) * scl;
        unsigned w0, w1;
        asm("v_cvt_pk_bf16_f32 %0, %1, %2" : "=v"(w0) : "v"(v0), "v"(v1));
        asm("v_cvt_pk_bf16_f32 %0, %1, %2" : "=v"(w1) : "v"(v2), "v"(v3));
        const int d2 = (wr * 64 + mi * 16 + g * 4) * 2;   // bytes within 256B
        *(uint2*)(sm + s_loc * 256 + (d2 ^ ((s_loc & 15) << 4))) = (uint2){w0, w1};
      }
    }
    __syncthreads();                        // packed tile visible
    // coalesced store: wave wid covers s rows wid*32..+31; 4 rows x 256B/instr
#pragma unroll
    for (int i = 0; i < 8; ++i) {
      const int s_loc = wid * 32 + i * 4 + (lane >> 4);
      const int db = (lane & 15) * 16;
      uint4 v = *(const uint4*)(sm + s_loc * 256 + (db ^ ((s_loc & 15) << 4)));
      *(uint4*)((unsigned char*)outp + (size_t)(n_blk + s_loc) * 1024 + m_blk * 2 + db) = v;
    }
  } else {
    // ---- Vs epilogue (unswapped): uint2 stores, tile-major [b][t][d][32] ----
    const int m0 = m_blk + wr * 64;
    const int n0 = n_blk + wc * 64;
#pragma unroll
    for (int ni = 0; ni < 4; ++ni) {
      int e = n0 + ni * 16 + c;
      float bb = biasv[e];
#pragma unroll
      for (int mi = 0; mi < 4; ++mi) {
        int row = m0 + mi * 16 + g * 4;       // 4 consecutive s for r=0..3
        int bi = row >> 11, sl = row & 2047;
        int t = sl >> 5, kvin = sl & 31;      // kvin 4-aligned
        union { unsigned short u[4]; uint2 v; } pk;
#pragma unroll
        for (int r = 0; r < 4; ++r) pk.u[r] = f2bf(acc[mi][ni][r] + bb);
        *(uint2*)(Vs + ((((size_t)bi * 64 + t) * 512) + e) * 32 + kvin) = pk.v;
      }
    }
  }
}

// ---------------- stage 2a: P = exp2(S' - 8*log2e), l = row-sums ------------
// SWAPPED operands: C = S^T (m=kv, n=q). 128x128, single-buffer 2-barrier,
// 256 thr, 4 blocks/CU (inter-block overlap covers epilogue — R21 lesson:
// T4 pipeline loses here at K=512 / 8 tiles). Epilogue packs bf16 P through
// LDS -> 8 coalesced uint4 stores.
__global__ __launch_bounds__(256, 4) void k_pa(
    const unsigned short* __restrict__ Qb, const unsigned short* __restrict__ Kb,
    unsigned short* __restrict__ P, float* __restrict__ l,
    int b_base, int bc) {
  __shared__ __align__(16) unsigned char smA[16384];
  __shared__ __align__(16) unsigned char smB[16384];
  const int lane = threadIdx.x & 63, wid = threadIdx.x >> 6;
  const int c = lane & 15, g = lane >> 4;
  const int wr = wid >> 1, wc = wid & 1;
  const int bloc = blockIdx.x % bc;
  const int tile = blockIdx.x / bc;
  const int b = b_base + bloc;
  const int m_blk = (tile & 15) * 128;      // kv
  const int n_blk = (tile >> 4) * 128;      // q
  unsigned short* Pb = P + (size_t)bloc * S_ * S_;

  const int src_sw = ((lane & 7) * 16) ^ (((lane >> 3) & 7) << 4);
  const unsigned char* ga = (const unsigned char*)(Kb + (size_t)b * S_ * D_)
      + (size_t)(m_blk + wid * 32 + (lane >> 3)) * 1024;   // A = K rows
  const unsigned char* gb = (const unsigned char*)(Qb + (size_t)b * S_ * D_)
      + (size_t)(n_blk + wid * 32 + (lane >> 3)) * 1024;   // B = Q rows
  unsigned char* la = smA + wid * 4096;
  unsigned char* lb = smB + wid * 4096;

  f32x4 acc[4][4];
#pragma unroll
  for (int mi = 0; mi < 4; ++mi)
#pragma unroll
    for (int ni = 0; ni < 4; ++ni) acc[mi][ni] = (f32x4){0.f, 0.f, 0.f, 0.f};

  for (int step = 0; step < 8; ++step) {
    __syncthreads();
#pragma unroll
    for (int i = 0; i < 4; ++i) {
      gl_lds16(ga + (size_t)i * 8192 + step * 128 + src_sw, la + i * 1024);
      gl_lds16(gb + (size_t)i * 8192 + step * 128 + src_sw, lb + i * 1024);
    }
    __syncthreads();
#pragma unroll
    for (int kc = 0; kc < 2; ++kc) {
      const int ro = (kc * 64 + g * 16) ^ ((c & 7) << 4);
      short8 af[4], bf[4];
#pragma unroll
      for (int mi = 0; mi < 4; ++mi)
        af[mi] = *(const short8*)(smA + (wr * 64 + mi * 16 + c) * 128 + ro);
#pragma unroll
      for (int ni = 0; ni < 4; ++ni)
        bf[ni] = *(const short8*)(smB + (wc * 64 + ni * 16 + c) * 128 + ro);
#pragma unroll
      for (int mi = 0; mi < 4; ++mi)
#pragma unroll
        for (int ni = 0; ni < 4; ++ni)
          acc[mi][ni] = __builtin_amdgcn_mfma_f32_16x16x32_bf16(af[mi], bf[ni], acc[mi][ni], 0, 0, 0);
    }
  }

  const float SH = 11.5415603f;             // 8*log2(e)
  float psum[4] = {0.f, 0.f, 0.f, 0.f};
  __syncthreads();                          // K-loop LDS reads done; smA free
#pragma unroll
  for (int ni = 0; ni < 4; ++ni) {
    const int q_loc = wc * 64 + ni * 16 + c;
#pragma unroll
    for (int mi = 0; mi < 4; ++mi) {
      float p0 = fexp2(acc[mi][ni][0] - SH);
      float p1 = fexp2(acc[mi][ni][1] - SH);
      float p2 = fexp2(acc[mi][ni][2] - SH);
      float p3 = fexp2(acc[mi][ni][3] - SH);
      psum[ni] += (p0 + p1) + (p2 + p3);
      unsigned w0, w1;
      asm("v_cvt_pk_bf16_f32 %0, %1, %2" : "=v"(w0) : "v"(p0), "v"(p1));
      asm("v_cvt_pk_bf16_f32 %0, %1, %2" : "=v"(w1) : "v"(p2), "v"(p3));
      const int kv2 = (wr * 64 + mi * 16 + g * 4) * 2;
      *(uint2*)(smA + q_loc * 256 + (kv2 ^ ((q_loc & 15) << 4))) = (uint2){w0, w1};
    }
  }
#pragma unroll
  for (int ni = 0; ni < 4; ++ni) {
    float v = psum[ni];
    v += __shfl_xor(v, 16);
    v += __shfl_xor(v, 32);
    if (g == 0)
      atomicAdd(l + b * S_ + n_blk + wc * 64 + ni * 16 + c, v);
  }
  __syncthreads();                          // packed tile visible
#pragma unroll
  for (int i = 0; i < 8; ++i) {
    const int q_loc = wid * 32 + i * 4 + (lane >> 4);
    const int kvb = (lane & 15) * 16;
    uint4 v = *(const uint4*)(smA + q_loc * 256 + (kvb ^ ((q_loc & 15) << 4)));
    *(uint4*)((unsigned char*)Pb + (size_t)(n_blk + q_loc) * 4096 + m_blk * 2 + kvb) = v;
  }
}

// ---------------- stage 2b: O = (P V) / l, computed as O^T ------------------
// Triple-buffered counted-vmcnt pipeline (T3+T4), verified R20 (+2.5 µs win;
// works here because K=2048 = 32 tiles amortizes the 2-tile prologue).
__global__ __launch_bounds__(512, 1) void k_pb(
    const unsigned short* __restrict__ P, const unsigned short* __restrict__ Vs,
    const float* __restrict__ l, float* __restrict__ out,
    int b_base, int bc) {
  __shared__ __align__(16) unsigned char sm[147456];  // 3 x {A 32KB + B 16KB}
  const int lane = threadIdx.x & 63, wid = threadIdx.x >> 6;  // wid 0..7
  const int c = lane & 15, g = lane >> 4;
  const int wm = wid >> 2, wn = wid & 3;    // wm: d-half(128), wn: q-quarter(32)
  const int bloc = blockIdx.x % bc;
  const int tile = blockIdx.x / bc;         // 0..31
  const int b = b_base + bloc;
  const int m_blk = (tile & 1) * 256;       // d
  const int n_blk = (tile >> 1) * 128;      // q
  const unsigned char* Pb = (const unsigned char*)(P + (size_t)bloc * S_ * S_);
  const unsigned char* Vsb = (const unsigned char*)(Vs + (size_t)b * 64 * 512 * 32);

  const int src_sw = ((lane & 7) * 16) ^ (((lane >> 3) & 7) << 4);
  const unsigned char* gA0 = Vsb + (size_t)(src_sw >> 6) * 32768
      + (size_t)(m_blk + (lane >> 3)) * 64 + (src_sw & 63);
  const unsigned char* gB0 = Pb + (size_t)(n_blk + (lane >> 3)) * 4096 + src_sw;

#define STG_A(h_, t_, bp_)                                                   \
  {                                                                          \
    _Pragma("unroll")                                                        \
    for (int i = 0; i < 2; ++i) {                                            \
      int rl = wid * 16 + i * 8;                                             \
      int pbv = (rl & 63) + ((rl & 64) << 1) + (h_) * 64;                    \
      gl_lds16(gA0 + (size_t)(t_) * 65536 + (size_t)pbv * 64,                \
               sm + (bp_) * 49152 + pbv * 128);                              \
    }                                                                        \
  }
#define STG_B(h_, t_, bp_)                                                   \
  {                                                                          \
    int rl = wid * 8;                                                        \
    int pbv = (rl & 8) + (h_) * 16 + ((rl >> 4) << 5);                       \
    gl_lds16(gB0 + (size_t)pbv * 4096 + (t_) * 128,                          \
             sm + (bp_) * 49152 + 32768 + pbv * 128);                        \
  }

  f32x4 acc[8][2];
#pragma unroll
  for (int a = 0; a < 8; ++a)
#pragma unroll
    for (int ni = 0; ni < 2; ++ni) acc[a][ni] = (f32x4){0.f, 0.f, 0.f, 0.f};

  STG_A(0, 0, 0); STG_B(0, 0, 0); STG_A(1, 0, 0); STG_B(1, 0, 0);
  STG_A(0, 1, 1); STG_B(0, 1, 1); STG_A(1, 1, 1); STG_B(1, 1, 1);

  for (int t = 0; t < 32; ++t) {
    const int cb = t % 3;
    const int nb = (t + 2) % 3;
    if (t < 31) asm volatile("s_waitcnt vmcnt(6)" ::: "memory");
    else        asm volatile("s_waitcnt vmcnt(0)" ::: "memory");
    __builtin_amdgcn_s_barrier();
    const unsigned char* Ab = sm + cb * 49152;
    const unsigned char* Bb = Ab + 32768;
    short8 bfr[2][2];
#pragma unroll
    for (int ni = 0; ni < 2; ++ni) {
      int row = wn * 32 + ni * 16 + c;
#pragma unroll
      for (int kc = 0; kc < 2; ++kc)
        bfr[ni][kc] = *(const short8*)(Bb + row * 128 + ((kc * 64 + g * 16) ^ ((c & 7) << 4)));
    }
    {
      short8 af[4][2];
#pragma unroll
      for (int mi = 0; mi < 4; ++mi) {
        int row = wm * 128 + mi * 16 + c;
#pragma unroll
        for (int kc = 0; kc < 2; ++kc)
          af[mi][kc] = *(const short8*)(Ab + row * 128 + ((kc * 64 + g * 16) ^ ((c & 7) << 4)));
      }
      if (t < 30) { STG_A(0, t + 2, nb); STG_B(0, t + 2, nb); }
      __builtin_amdgcn_s_setprio(1);
#pragma unroll
      for (int kc = 0; kc < 2; ++kc)
#pragma unroll
        for (int mi = 0; mi < 4; ++mi)
#pragma unroll
          for (int ni = 0; ni < 2; ++ni)
            acc[mi][ni] = __builtin_amdgcn_mfma_f32_16x16x32_bf16(af[mi][kc], bfr[ni][kc], acc[mi][ni], 0, 0, 0);
      __builtin_amdgcn_s_setprio(0);
    }
    {
      short8 af[4][2];
#pragma unroll
      for (int mi = 0; mi < 4; ++mi) {
        int row = wm * 128 + 64 + mi * 16 + c;
#pragma unroll
        for (int kc = 0; kc < 2; ++kc)
          af[mi][kc] = *(const short8*)(Ab + row * 128 + ((kc * 64 + g * 16) ^ ((c & 7) << 4)));
      }
      if (t < 30) { STG_A(1, t + 2, nb); STG_B(1, t + 2, nb); }
      __builtin_amdgcn_s_setprio(1);
#pragma unroll
      for (int kc = 0; kc < 2; ++kc)
#pragma unroll
        for (int mi = 0; mi < 4; ++mi)
#pragma unroll
          for (int ni = 0; ni < 2; ++ni)
            acc[4 + mi][ni] = __builtin_amdgcn_mfma_f32_16x16x32_bf16(af[mi][kc], bfr[ni][kc], acc[4 + mi][ni], 0, 0, 0);
      __builtin_amdgcn_s_setprio(0);
    }
  }
#undef STG_A
#undef STG_B

  float* ob = out + (size_t)b * S_ * D_;
#pragma unroll
  for (int ni = 0; ni < 2; ++ni) {
    const int q = n_blk + wn * 32 + ni * 16 + c;
    const float inv = 1.f / l[b * S_ + q];
#pragma unroll
    for (int a = 0; a < 8; ++a) {
      const int d0 = m_blk + wm * 128 + (a >> 2) * 64 + (a & 3) * 16 + g * 4;
      float4 v;
      v.x = acc[a][ni][0] * inv; v.y = acc[a][ni][1] * inv;
      v.z = acc[a][ni][2] * inv; v.w = acc[a][ni][3] * inv;
      *(float4*)(ob + (size_t)q * D_ + d0) = v;
    }
  }
}

// ---------------- launch ----------------------------------------------------
extern "C" void kernel_launch(void* const* d_in, const int* in_sizes, int n_in,
                              void* d_out, int out_size, void* d_ws, size_t ws_size,
                              hipStream_t stream) {
  const float* x  = (const float*)d_in[0];
  const float* Wq = (const float*)d_in[1];
  const float* bq = (const float*)d_in[2];
  const float* Wk = (const float*)d_in[3];
  const float* bk = (const float*)d_in[4];
  const float* Wv = (const float*)d_in[5];
  const float* bv = (const float*)d_in[6];
  float* out = (float*)d_out;

  // workspace layout (bf16 unless noted)
  unsigned short* xb = (unsigned short*)d_ws;              // [16384][512]  (dead after k_qkv)
  unsigned short* Wt = xb + (size_t)16384 * 512;           // [3][512][512] (dead after k_qkv)
  unsigned short* Qb = Wt + (size_t)3 * 512 * 512;         // [16384][512], pre-scaled
  unsigned short* Kb = Qb + (size_t)16384 * 512;           // [16384][512]
  unsigned short* Vs = Kb + (size_t)16384 * 512;           // [8][64][512][32] tile-major
  float* l = (float*)(Vs + (size_t)8 * 64 * 512 * 32);     // [8][2048] f32 — OWN slot
  unsigned short* Pfull = (unsigned short*)(l + 8 * 2048); // [8][2048][2048] (if ws allows)
  const size_t full_need =
      (size_t)((unsigned char*)(Pfull + (size_t)8 * 2048 * 2048) - (unsigned char*)d_ws);

  k_prep<<<dim3(7232), dim3(256), 0, stream>>>(x, Wq, Wk, Wv, xb, Wt, l);
  k_qkv<<<dim3(128, 4, 3), dim3(256), 0, stream>>>(xb, Wt, bq, bk, bv, Qb, Kb, Vs);

  if (ws_size >= full_need) {
    k_pa<<<dim3(2048), dim3(256), 0, stream>>>(Qb, Kb, Pfull, l, 0, 8);
    k_pb<<<dim3(256),  dim3(512), 0, stream>>>(Pfull, Vs, l, out, 0, 8);
  } else {
    // 2 batches of P fit exactly in the dead xb region (16.7 MB).
    unsigned short* P2 = xb;
    for (int g2 = 0; g2 < 4; ++g2) {
      k_pa<<<dim3(512), dim3(256), 0, stream>>>(Qb, Kb, P2, l, g2 * 2, 2);
      k_pb<<<dim3(64), dim3(512), 0, stream>>>(P2, Vs, l, out, g2 * 2, 2);
    }
  }
}